// Round 10
// baseline (9247.919 us; speedup 1.0000x reference)
//
#include <hip/hip_runtime.h>
#include <hip/hip_bf16.h>

typedef float f32x16 __attribute__((ext_vector_type(16)));
typedef unsigned int u32;
typedef unsigned short u16;

#define DT 0.01f

// sin(x) with Cody-Waite reduction mod pi, accurate to ~2e-7 for |x| < ~6000.
__device__ __forceinline__ float fast_sin(float x) {
  const float INVPI = 0.3183098861837907f;
  float n = rintf(x * INVPI);
  int ni = (int)n;
  float r = fmaf(n, -3.140625f, x);          // n*3.140625 exact for |n| < 2^12
  r = fmaf(n, -9.6765358979e-4f, r);         // pi - 3.140625
  float s = r * r;
  float p = fmaf(s, -2.5052108e-8f, 2.7557319e-6f);
  p = fmaf(s, p, -1.9841270e-4f);
  p = fmaf(s, p, 8.3333333e-3f);
  p = fmaf(s, p, -1.6666667e-1f);
  float res = fmaf(r * s, p, r);             // sin(r), |r| <= pi/2
  return (ni & 1) ? -res : res;              // sin(x) = (-1)^n sin(r)
}

// 4x s_load_dwordx16 from a wave-uniform address + waitcnt, all in one asm
// block. Outputs live in SGPRs; consuming FMAs read them as the free scalar
// operand of v_fmac_f32.
__device__ __forceinline__ void sload4(const float* p, f32x16& a, f32x16& b,
                                       f32x16& c, f32x16& d) {
  asm volatile(
      "s_load_dwordx16 %0, %4, 0\n\t"
      "s_load_dwordx16 %1, %4, 0x40\n\t"
      "s_load_dwordx16 %2, %4, 0x80\n\t"
      "s_load_dwordx16 %3, %4, 0xc0\n\t"
      "s_waitcnt lgkmcnt(0)"
      : "=s"(a), "=s"(b), "=s"(c), "=s"(d)
      : "s"(p));
}

// K0s[h,j] = sum_m k0[h,m,j]   (k0: [128,512,512])
__global__ __launch_bounds__(256) void kPrep1(const float* __restrict__ k0,
                                              float* __restrict__ K0s) {
  int t = blockIdx.x * 256 + threadIdx.x;     // 65536 threads
  int h = t >> 9, j = t & 511;
  const float* p = k0 + (size_t)h * 262144 + j;
  float s = 0.f;
  for (int m = 0; m < 512; ++m) s += p[(size_t)m * 512];
  K0s[t] = s;
}

// K1s[h,j] = sum_m k1[h,m,j]   (k1: [128,512,128])
__global__ __launch_bounds__(256) void kPrep2(const float* __restrict__ k1,
                                              float* __restrict__ K1s) {
  int t = blockIdx.x * 256 + threadIdx.x;     // 16384 threads
  int h = t >> 7, j = t & 127;
  const float* p = k1 + (size_t)h * 65536 + j;
  float s = 0.f;
  for (int m = 0; m < 512; ++m) s += p[(size_t)m * 128];
  K1s[t] = s;
}

// M[l,j] = sum_h K1s[l,h] * K0s[h,j]   ([128,512] = K1s @ K0s)
__global__ __launch_bounds__(256) void kPrep3(const float* __restrict__ K0s,
                                              const float* __restrict__ K1s,
                                              float* __restrict__ M) {
  int t = blockIdx.x * 256 + threadIdx.x;     // 65536 threads
  int l = t >> 9, j = t & 511;
  float s = 0.f;
#pragma unroll 8
  for (int h = 0; h < 128; ++h) s = fmaf(K1s[l * 128 + h], K0s[h * 512 + j], s);
  M[t] = s;
}

// Per-row int16 quantization of k2, written in the COMPUTE-coalesced layout
// kqT[l][jb][m][8] (jb=j/8): thread t of kBi16 then reads one uint4 per jb at
// consecutive-lane-consecutive-address. 16 threads per row (8 j each), row
// max via 16-lane xor-shuffle. Values/order identical to the R9 quantizer.
__global__ __launch_bounds__(256) void kConvRow(const float* __restrict__ k2,
                                                short* __restrict__ kqT,
                                                float* __restrict__ rowinv) {
  const int t = threadIdx.x;
  const int row = blockIdx.x * 16 + (t >> 4);  // (l,m) row
  const int seg = t & 15;                      // = jb
  const float* src = k2 + (size_t)row * 128 + seg * 8;
  const float4 a = *(const float4*)(src);
  const float4 b = *(const float4*)(src + 4);
  float m = fmaxf(fmaxf(fmaxf(fabsf(a.x), fabsf(a.y)), fmaxf(fabsf(a.z), fabsf(a.w))),
                  fmaxf(fmaxf(fabsf(b.x), fabsf(b.y)), fmaxf(fabsf(b.z), fabsf(b.w))));
#pragma unroll
  for (int off = 8; off > 0; off >>= 1) m = fmaxf(m, __shfl_xor(m, off, 64));
  const float scale = m > 0.f ? 32767.0f / m : 0.f;
  if (seg == 0) rowinv[row] = m > 0.f ? m / 32767.0f : 0.f;
  uint4 o;
  o.x = (u32)(u16)(short)rintf(a.x * scale) | ((u32)(u16)(short)rintf(a.y * scale) << 16);
  o.y = (u32)(u16)(short)rintf(a.z * scale) | ((u32)(u16)(short)rintf(a.w * scale) << 16);
  o.z = (u32)(u16)(short)rintf(b.x * scale) | ((u32)(u16)(short)rintf(b.y * scale) << 16);
  o.w = (u32)(u16)(short)rintf(b.z * scale) | ((u32)(u16)(short)rintf(b.w * scale) << 16);
  const int l = row >> 9, mm = row & 511;
  *(uint4*)(kqT + (((size_t)l * 16 + seg) * 512 + mm) * 8) = o;
}

// Kernel A: RK4 bookkeeping + s2T = transpose(M * y_stage).
__global__ __launch_bounds__(256) void kA(
    const float* __restrict__ y0, const float* __restrict__ bias,
    const float* __restrict__ M, const float* __restrict__ aggp,
    float* __restrict__ ybuf,    // [2][16][512]
    float* __restrict__ racc,    // [16][512]
    float* __restrict__ s2T,     // [128][16]  (j-major, b contiguous)
    float* __restrict__ out,     // [8][16][512]
    int stage, int step) {
  __shared__ float ystage[512];
  __shared__ float red[256];
  const int b = blockIdx.x >> 2, q = blockIdx.x & 3, t = threadIdx.x;
  const float* ycur = ybuf + (step & 1) * 8192;
  float* ynext = ybuf + ((step + 1) & 1) * 8192;

  for (int i = t; i < 512; i += 256) {
    const int idx = b * 512 + i;
    const bool own = (i >> 7) == q;
    float ys;
    if (stage == 0) {
      ys = y0[idx];
      if (own) ynext[idx] = ys;
    } else {
      const float r = bias[idx] - (aggp[idx] + aggp[8192 + idx]);
      const float yb = ycur[idx];
      if (stage == 1) {
        ys = fmaf(0.5f * DT, r, yb);
        if (own) racc[idx] = r;
      } else if (stage == 2) {
        ys = fmaf(0.5f * DT, r, yb);
        if (own) racc[idx] = racc[idx] + 2.f * r;
      } else if (stage == 3) {
        ys = fmaf(DT, r, yb);
        if (own) racc[idx] = racc[idx] + 2.f * r;
      } else {
        ys = yb + (DT / 6.f) * (racc[idx] + r);
        if (own) { ynext[idx] = ys; out[step * 8192 + idx] = ys; }
      }
    }
    ystage[i] = ys;
  }
  __syncthreads();

  const int l = q * 32 + (t >> 3), seg = t & 7;
  const float* Mrow = M + l * 512 + seg * 64;
  float p = 0.f;
#pragma unroll 8
  for (int i = 0; i < 64; ++i) p = fmaf(Mrow[i], ystage[seg * 64 + i], p);
  red[t] = p;
  __syncthreads();
  if (seg == 0) {
    float ssum = 0.f;
#pragma unroll
    for (int k = 0; k < 8; ++k) ssum += red[t + k];
    s2T[l * 16 + b] = ssum;
  }
}

// Kernel B (int16 k2, transposed layout): NO LDS, NO barriers in the main
// loop. Thread t handles row (l, m=half*256+t); per jb it reads one
// perfectly-coalesced uint4 of kqT (consecutive lanes -> consecutive 16B).
// 16 independent loads + barrier-free code let the compiler hoist loads and
// hide latency with ILP+TLP (k2 has zero intra-dispatch reuse — LDS staging
// was only ever a coalescing device, now obsolete). s2 via SGPR broadcasts.
__global__ __launch_bounds__(256) void kBi16(
    const short* __restrict__ kqT, const float* __restrict__ adj,
    const float* __restrict__ s2T, const float* __restrict__ rowinv,
    float* __restrict__ aggp) {
  __shared__ float part[64];
  const int t = threadIdx.x;
  const int rid0 = blockIdx.x * 256;
  const int rid = rid0 + t;
  const int l = rid0 >> 9;
  const int half = blockIdx.x & 1;
  const int m = half * 256 + t;

  float dot[16];
#pragma unroll
  for (int b = 0; b < 16; ++b) dot[b] = 0.f;

#pragma unroll
  for (int jb = 0; jb < 16; ++jb) {
    const uint4 kw = *(const uint4*)(kqT + (((size_t)l * 16 + jb) * 512 + m) * 8);
    const int j0 = jb * 8;
    f32x16 sa, sb, sc, sd;
    {
      const float f0 = (float)(short)(kw.x & 0xFFFFu);
      const float f1 = (float)(short)(kw.x >> 16);
      const float f2 = (float)(short)(kw.y & 0xFFFFu);
      const float f3 = (float)(short)(kw.y >> 16);
      sload4(s2T + j0 * 16, sa, sb, sc, sd);
#pragma unroll
      for (int b = 0; b < 16; ++b) dot[b] = fmaf(sa[b], f0, dot[b]);
#pragma unroll
      for (int b = 0; b < 16; ++b) dot[b] = fmaf(sb[b], f1, dot[b]);
#pragma unroll
      for (int b = 0; b < 16; ++b) dot[b] = fmaf(sc[b], f2, dot[b]);
#pragma unroll
      for (int b = 0; b < 16; ++b) dot[b] = fmaf(sd[b], f3, dot[b]);
    }
    {
      const float f4 = (float)(short)(kw.z & 0xFFFFu);
      const float f5 = (float)(short)(kw.z >> 16);
      const float f6 = (float)(short)(kw.w & 0xFFFFu);
      const float f7 = (float)(short)(kw.w >> 16);
      sload4(s2T + (j0 + 4) * 16, sa, sb, sc, sd);
#pragma unroll
      for (int b = 0; b < 16; ++b) dot[b] = fmaf(sa[b], f4, dot[b]);
#pragma unroll
      for (int b = 0; b < 16; ++b) dot[b] = fmaf(sb[b], f5, dot[b]);
#pragma unroll
      for (int b = 0; b < 16; ++b) dot[b] = fmaf(sc[b], f6, dot[b]);
#pragma unroll
      for (int b = 0; b < 16; ++b) dot[b] = fmaf(sd[b], f7, dot[b]);
    }
  }

  const float rinv = rowinv[rid];
#pragma unroll
  for (int b = 0; b < 16; ++b) {
    float v = adj[(size_t)b * 262144 + rid] * fast_sin(dot[b] * rinv);
#pragma unroll
    for (int off = 32; off > 0; off >>= 1) v += __shfl_down(v, off, 64);
    if ((t & 63) == 0) part[(t >> 6) * 16 + b] = v;
  }
  __syncthreads();
  if (t < 16) {
    float ssum = part[t] + part[16 + t] + part[32 + t] + part[48 + t];
    aggp[half * 8192 + t * 512 + l] = ssum;   // aggp[half][b][l]
  }
}

// Kernel B fallback (fp32 k2, R4 body) — only if ws_size can't hold int16.
__global__ __launch_bounds__(256) void kBf32(
    const float* __restrict__ k2, const float* __restrict__ adj,
    const float* __restrict__ s2T, float* __restrict__ aggp) {
  __shared__ float lk[256 * 36];
  __shared__ float part[64];
  const int t = threadIdx.x;
  const int rid0 = blockIdx.x * 256;
  const int rid = rid0 + t;
  const int l = rid0 >> 9;
  const int half = blockIdx.x & 1;

  float dot[16];
#pragma unroll
  for (int b = 0; b < 16; ++b) dot[b] = 0.f;

  for (int c = 0; c < 4; ++c) {
    __syncthreads();
#pragma unroll
    for (int k = 0; k < 8; ++k) {
      const int f = k * 256 + t, row = f >> 3, e = f & 7;
      const float4 v = *(const float4*)(k2 + (size_t)(rid0 + row) * 128 + c * 32 + e * 4);
      *(float4*)(lk + row * 36 + e * 4) = v;
    }
    __syncthreads();
    const float* myrow = lk + t * 36;
#pragma unroll
    for (int q = 0; q < 8; ++q) {
      const float4 kv = *(const float4*)(myrow + q * 4);
      f32x16 sa, sb, sc, sd;
      sload4(s2T + (c * 32 + q * 4) * 16, sa, sb, sc, sd);
#pragma unroll
      for (int b = 0; b < 16; ++b) dot[b] = fmaf(sa[b], kv.x, dot[b]);
#pragma unroll
      for (int b = 0; b < 16; ++b) dot[b] = fmaf(sb[b], kv.y, dot[b]);
#pragma unroll
      for (int b = 0; b < 16; ++b) dot[b] = fmaf(sc[b], kv.z, dot[b]);
#pragma unroll
      for (int b = 0; b < 16; ++b) dot[b] = fmaf(sd[b], kv.w, dot[b]);
    }
  }

#pragma unroll
  for (int b = 0; b < 16; ++b) {
    float v = adj[(size_t)b * 262144 + rid] * fast_sin(dot[b]);
#pragma unroll
    for (int off = 32; off > 0; off >>= 1) v += __shfl_down(v, off, 64);
    if ((t & 63) == 0) part[(t >> 6) * 16 + b] = v;
  }
  __syncthreads();
  if (t < 16) {
    float ssum = part[t] + part[16 + t] + part[32 + t] + part[48 + t];
    aggp[half * 8192 + t * 512 + l] = ssum;
  }
}

extern "C" void kernel_launch(void* const* d_in, const int* in_sizes, int n_in,
                              void* d_out, int out_size, void* d_ws, size_t ws_size,
                              hipStream_t stream) {
  const float* y0   = (const float*)d_in[0];  // [16,512]
  const float* bias = (const float*)d_in[1];  // [16,512,1]
  const float* adj  = (const float*)d_in[2];  // [16,512,512]
  const float* k0   = (const float*)d_in[3];  // [128,512,512]
  const float* k1   = (const float*)d_in[4];  // [128,512,128]
  const float* k2   = (const float*)d_in[5];  // [512,512,128]
  float* out = (float*)d_out;                 // [8,16,512] f32

  float* w      = (float*)d_ws;
  float* K0s    = w;               // 65536 floats
  float* K1s    = w + 65536;       // 16384
  float* M      = w + 81920;       // 65536
  float* s2T    = w + 147456;      // 2048  ([128][16] transposed)
  float* ybuf   = w + 149504;      // 16384 (2 x 8192, ping-pong)
  float* racc   = w + 165888;      // 8192
  float* aggp   = w + 174080;      // 16384 (2 halves x [16][512])
  float* rowinv = w + 190464;      // 262144 floats = 1 MB
  short* kqT    = (short*)(w + 190464 + 262144);  // 33554432 shorts = 64 MB
  const bool useI16 =
      ws_size >= (size_t)(190464 + 262144) * 4 + (size_t)33554432 * 2;

  kPrep1<<<256, 256, 0, stream>>>(k0, K0s);
  kPrep2<<<64, 256, 0, stream>>>(k1, K1s);
  kPrep3<<<256, 256, 0, stream>>>(K0s, K1s, M);
  if (useI16) kConvRow<<<16384, 256, 0, stream>>>(k2, kqT, rowinv);

  kA<<<64, 256, 0, stream>>>(y0, bias, M, aggp, ybuf, racc, s2T, out, 0, -1);

  for (int step = 0; step < 8; ++step) {
    for (int stage = 1; stage <= 4; ++stage) {
      if (useI16)
        kBi16<<<1024, 256, 0, stream>>>(kqT, adj, s2T, rowinv, aggp);
      else
        kBf32<<<1024, 256, 0, stream>>>(k2, adj, s2T, aggp);
      kA<<<64, 256, 0, stream>>>(y0, bias, M, aggp, ybuf, racc, s2T, out, stage, step);
    }
  }
}

// Round 11
// 1105.180 us; speedup vs baseline: 8.3678x; 8.3678x over previous
//
#include <hip/hip_runtime.h>
#include <hip/hip_bf16.h>

typedef float f32x16 __attribute__((ext_vector_type(16)));
typedef unsigned int u32;
typedef unsigned short u16;

#define DT 0.01f

// sin(x) with Cody-Waite reduction mod pi, accurate to ~2e-7 for |x| < ~6000.
__device__ __forceinline__ float fast_sin(float x) {
  const float INVPI = 0.3183098861837907f;
  float n = rintf(x * INVPI);
  int ni = (int)n;
  float r = fmaf(n, -3.140625f, x);          // n*3.140625 exact for |n| < 2^12
  r = fmaf(n, -9.6765358979e-4f, r);         // pi - 3.140625
  float s = r * r;
  float p = fmaf(s, -2.5052108e-8f, 2.7557319e-6f);
  p = fmaf(s, p, -1.9841270e-4f);
  p = fmaf(s, p, 8.3333333e-3f);
  p = fmaf(s, p, -1.6666667e-1f);
  float res = fmaf(r * s, p, r);             // sin(r), |r| <= pi/2
  return (ni & 1) ? -res : res;              // sin(x) = (-1)^n sin(r)
}

// 4x s_load_dwordx16 from a wave-uniform address + waitcnt, all in one asm
// block. Outputs live in SGPRs; consuming FMAs read them as the free scalar
// operand of v_fmac_f32.
__device__ __forceinline__ void sload4(const float* p, f32x16& a, f32x16& b,
                                       f32x16& c, f32x16& d) {
  asm volatile(
      "s_load_dwordx16 %0, %4, 0\n\t"
      "s_load_dwordx16 %1, %4, 0x40\n\t"
      "s_load_dwordx16 %2, %4, 0x80\n\t"
      "s_load_dwordx16 %3, %4, 0xc0\n\t"
      "s_waitcnt lgkmcnt(0)"
      : "=s"(a), "=s"(b), "=s"(c), "=s"(d)
      : "s"(p));
}

// K0s[h,j] = sum_m k0[h,m,j]   (k0: [128,512,512])
__global__ __launch_bounds__(256) void kPrep1(const float* __restrict__ k0,
                                              float* __restrict__ K0s) {
  int t = blockIdx.x * 256 + threadIdx.x;     // 65536 threads
  int h = t >> 9, j = t & 511;
  const float* p = k0 + (size_t)h * 262144 + j;
  float s = 0.f;
  for (int m = 0; m < 512; ++m) s += p[(size_t)m * 512];
  K0s[t] = s;
}

// K1s[h,j] = sum_m k1[h,m,j]   (k1: [128,512,128])
__global__ __launch_bounds__(256) void kPrep2(const float* __restrict__ k1,
                                              float* __restrict__ K1s) {
  int t = blockIdx.x * 256 + threadIdx.x;     // 16384 threads
  int h = t >> 7, j = t & 127;
  const float* p = k1 + (size_t)h * 65536 + j;
  float s = 0.f;
  for (int m = 0; m < 512; ++m) s += p[(size_t)m * 128];
  K1s[t] = s;
}

// M[l,j] = sum_h K1s[l,h] * K0s[h,j]   ([128,512] = K1s @ K0s)
__global__ __launch_bounds__(256) void kPrep3(const float* __restrict__ K0s,
                                              const float* __restrict__ K1s,
                                              float* __restrict__ M) {
  int t = blockIdx.x * 256 + threadIdx.x;     // 65536 threads
  int l = t >> 9, j = t & 511;
  float s = 0.f;
#pragma unroll 8
  for (int h = 0; h < 128; ++h) s = fmaf(K1s[l * 128 + h], K0s[h * 512 + j], s);
  M[t] = s;
}

// Per-row int16 quantization of k2 (row-major kq, R9 layout): 16 threads per
// row (8 elems each), row max via 16-lane xor-shuffle, q = rint(k2*32767/max).
__global__ __launch_bounds__(256) void kConvRow(const float* __restrict__ k2,
                                                short* __restrict__ kq,
                                                float* __restrict__ rowinv) {
  const int t = threadIdx.x;
  const int row = blockIdx.x * 16 + (t >> 4);
  const int seg = t & 15;
  const float* src = k2 + (size_t)row * 128 + seg * 8;
  const float4 a = *(const float4*)(src);
  const float4 b = *(const float4*)(src + 4);
  float m = fmaxf(fmaxf(fmaxf(fabsf(a.x), fabsf(a.y)), fmaxf(fabsf(a.z), fabsf(a.w))),
                  fmaxf(fmaxf(fabsf(b.x), fabsf(b.y)), fmaxf(fabsf(b.z), fabsf(b.w))));
#pragma unroll
  for (int off = 8; off > 0; off >>= 1) m = fmaxf(m, __shfl_xor(m, off, 64));
  const float scale = m > 0.f ? 32767.0f / m : 0.f;
  if (seg == 0) rowinv[row] = m > 0.f ? m / 32767.0f : 0.f;
  uint4 o;
  o.x = (u32)(u16)(short)rintf(a.x * scale) | ((u32)(u16)(short)rintf(a.y * scale) << 16);
  o.y = (u32)(u16)(short)rintf(a.z * scale) | ((u32)(u16)(short)rintf(a.w * scale) << 16);
  o.z = (u32)(u16)(short)rintf(b.x * scale) | ((u32)(u16)(short)rintf(b.y * scale) << 16);
  o.w = (u32)(u16)(short)rintf(b.z * scale) | ((u32)(u16)(short)rintf(b.w * scale) << 16);
  *(uint4*)(kq + (size_t)row * 128 + seg * 8) = o;
}

// Kernel A: RK4 bookkeeping + s2T = transpose(M * y_stage).
__global__ __launch_bounds__(256) void kA(
    const float* __restrict__ y0, const float* __restrict__ bias,
    const float* __restrict__ M, const float* __restrict__ aggp,
    float* __restrict__ ybuf,    // [2][16][512]
    float* __restrict__ racc,    // [16][512]
    float* __restrict__ s2T,     // [128][16]  (j-major, b contiguous)
    float* __restrict__ out,     // [8][16][512]
    int stage, int step) {
  __shared__ float ystage[512];
  __shared__ float red[256];
  const int b = blockIdx.x >> 2, q = blockIdx.x & 3, t = threadIdx.x;
  const float* ycur = ybuf + (step & 1) * 8192;
  float* ynext = ybuf + ((step + 1) & 1) * 8192;

  for (int i = t; i < 512; i += 256) {
    const int idx = b * 512 + i;
    const bool own = (i >> 7) == q;
    float ys;
    if (stage == 0) {
      ys = y0[idx];
      if (own) ynext[idx] = ys;
    } else {
      const float r = bias[idx] - (aggp[idx] + aggp[8192 + idx]);
      const float yb = ycur[idx];
      if (stage == 1) {
        ys = fmaf(0.5f * DT, r, yb);
        if (own) racc[idx] = r;
      } else if (stage == 2) {
        ys = fmaf(0.5f * DT, r, yb);
        if (own) racc[idx] = racc[idx] + 2.f * r;
      } else if (stage == 3) {
        ys = fmaf(DT, r, yb);
        if (own) racc[idx] = racc[idx] + 2.f * r;
      } else {
        ys = yb + (DT / 6.f) * (racc[idx] + r);
        if (own) { ynext[idx] = ys; out[step * 8192 + idx] = ys; }
      }
    }
    ystage[i] = ys;
  }
  __syncthreads();

  const int l = q * 32 + (t >> 3), seg = t & 7;
  const float* Mrow = M + l * 512 + seg * 64;
  float p = 0.f;
#pragma unroll 8
  for (int i = 0; i < 64; ++i) p = fmaf(Mrow[i], ystage[seg * 64 + i], p);
  red[t] = p;
  __syncthreads();
  if (seg == 0) {
    float ssum = 0.f;
#pragma unroll
    for (int k = 0; k < 8; ++k) ssum += red[t + k];
    s2T[l * 16 + b] = ssum;
  }
}

// Kernel B (int16 k2): WAVE-PRIVATE staging, NO __syncthreads in main loop.
// Wave w stages rows [w*64, w*64+64) (one wave-load = 8 full 128B lines,
// coalescing is a wave property) and its own threads consume exactly those
// rows -> write->read ordering is the wave's in-order DS pipe + lgkmcnt, no
// barrier. Without the WG barriers the 16 waves/CU free-run, so HBM staging
// of some waves overlaps FMA of others (the overlap 4 rounds of explicit
// pipelining failed to get). LDS stride 72 shorts (144B) = proven 0-conflict.
__global__ __launch_bounds__(256) void kBi16(
    const short* __restrict__ kq, const float* __restrict__ adj,
    const float* __restrict__ s2T, const float* __restrict__ rowinv,
    float* __restrict__ aggp) {
  __shared__ short lk[256 * 72];   // 36,864 B
  __shared__ float part[64];
  const int t = threadIdx.x;
  const int rid0 = blockIdx.x * 256;
  const int rid = rid0 + t;
  const int l = rid0 >> 9;
  const int half = blockIdx.x & 1;
  const int w = t >> 6, lane = t & 63;

  float dot[16];
#pragma unroll
  for (int b = 0; b < 16; ++b) dot[b] = 0.f;
  float av[16];

  for (int c = 0; c < 2; ++c) {    // two 64-j chunks
    // wave-private stage: 8 uint4 per lane covering this wave's 64 rows
#pragma unroll
    for (int k = 0; k < 8; ++k) {
      const int g = k * 64 + lane;               // 0..511
      const int row = w * 64 + (g >> 3), e = g & 7;
      const uint4 v = *(const uint4*)(kq + (size_t)(rid0 + row) * 128 + c * 64 + e * 8);
      *(uint4*)(lk + row * 72 + e * 8) = v;
    }
    if (c == 1) {                  // adj prefetch, in-flight under chunk-1 FMA
#pragma unroll
      for (int b = 0; b < 16; ++b) av[b] = adj[(size_t)b * 262144 + rid];
    }
    const short* myrow = lk + t * 72;
#pragma unroll
    for (int qq = 0; qq < 8; ++qq) {
      const uint4 kw = *(const uint4*)(myrow + qq * 8);   // 8 shorts = 8 j
      const int j0 = c * 64 + qq * 8;
      f32x16 sa, sb, sc, sd;
      {
        const float f0 = (float)(short)(kw.x & 0xFFFFu);
        const float f1 = (float)(short)(kw.x >> 16);
        const float f2 = (float)(short)(kw.y & 0xFFFFu);
        const float f3 = (float)(short)(kw.y >> 16);
        sload4(s2T + j0 * 16, sa, sb, sc, sd);
#pragma unroll
        for (int b = 0; b < 16; ++b) dot[b] = fmaf(sa[b], f0, dot[b]);
#pragma unroll
        for (int b = 0; b < 16; ++b) dot[b] = fmaf(sb[b], f1, dot[b]);
#pragma unroll
        for (int b = 0; b < 16; ++b) dot[b] = fmaf(sc[b], f2, dot[b]);
#pragma unroll
        for (int b = 0; b < 16; ++b) dot[b] = fmaf(sd[b], f3, dot[b]);
      }
      {
        const float f4 = (float)(short)(kw.z & 0xFFFFu);
        const float f5 = (float)(short)(kw.z >> 16);
        const float f6 = (float)(short)(kw.w & 0xFFFFu);
        const float f7 = (float)(short)(kw.w >> 16);
        sload4(s2T + (j0 + 4) * 16, sa, sb, sc, sd);
#pragma unroll
        for (int b = 0; b < 16; ++b) dot[b] = fmaf(sa[b], f4, dot[b]);
#pragma unroll
        for (int b = 0; b < 16; ++b) dot[b] = fmaf(sb[b], f5, dot[b]);
#pragma unroll
        for (int b = 0; b < 16; ++b) dot[b] = fmaf(sc[b], f6, dot[b]);
#pragma unroll
        for (int b = 0; b < 16; ++b) dot[b] = fmaf(sd[b], f7, dot[b]);
      }
    }
  }

  const float rinv = rowinv[rid];
#pragma unroll
  for (int b = 0; b < 16; ++b) {
    float v = av[b] * fast_sin(dot[b] * rinv);
#pragma unroll
    for (int off = 32; off > 0; off >>= 1) v += __shfl_down(v, off, 64);
    if ((t & 63) == 0) part[(t >> 6) * 16 + b] = v;
  }
  __syncthreads();
  if (t < 16) {
    float ssum = part[t] + part[16 + t] + part[32 + t] + part[48 + t];
    aggp[half * 8192 + t * 512 + l] = ssum;   // aggp[half][b][l]
  }
}

// Kernel B fallback (fp32 k2, R4 body) — only if ws_size can't hold int16.
__global__ __launch_bounds__(256) void kBf32(
    const float* __restrict__ k2, const float* __restrict__ adj,
    const float* __restrict__ s2T, float* __restrict__ aggp) {
  __shared__ float lk[256 * 36];
  __shared__ float part[64];
  const int t = threadIdx.x;
  const int rid0 = blockIdx.x * 256;
  const int rid = rid0 + t;
  const int l = rid0 >> 9;
  const int half = blockIdx.x & 1;

  float dot[16];
#pragma unroll
  for (int b = 0; b < 16; ++b) dot[b] = 0.f;

  for (int c = 0; c < 4; ++c) {
    __syncthreads();
#pragma unroll
    for (int k = 0; k < 8; ++k) {
      const int f = k * 256 + t, row = f >> 3, e = f & 7;
      const float4 v = *(const float4*)(k2 + (size_t)(rid0 + row) * 128 + c * 32 + e * 4);
      *(float4*)(lk + row * 36 + e * 4) = v;
    }
    __syncthreads();
    const float* myrow = lk + t * 36;
#pragma unroll
    for (int q = 0; q < 8; ++q) {
      const float4 kv = *(const float4*)(myrow + q * 4);
      f32x16 sa, sb, sc, sd;
      sload4(s2T + (c * 32 + q * 4) * 16, sa, sb, sc, sd);
#pragma unroll
      for (int b = 0; b < 16; ++b) dot[b] = fmaf(sa[b], kv.x, dot[b]);
#pragma unroll
      for (int b = 0; b < 16; ++b) dot[b] = fmaf(sb[b], kv.y, dot[b]);
#pragma unroll
      for (int b = 0; b < 16; ++b) dot[b] = fmaf(sc[b], kv.z, dot[b]);
#pragma unroll
      for (int b = 0; b < 16; ++b) dot[b] = fmaf(sd[b], kv.w, dot[b]);
    }
  }

#pragma unroll
  for (int b = 0; b < 16; ++b) {
    float v = adj[(size_t)b * 262144 + rid] * fast_sin(dot[b]);
#pragma unroll
    for (int off = 32; off > 0; off >>= 1) v += __shfl_down(v, off, 64);
    if ((t & 63) == 0) part[(t >> 6) * 16 + b] = v;
  }
  __syncthreads();
  if (t < 16) {
    float ssum = part[t] + part[16 + t] + part[32 + t] + part[48 + t];
    aggp[half * 8192 + t * 512 + l] = ssum;
  }
}

extern "C" void kernel_launch(void* const* d_in, const int* in_sizes, int n_in,
                              void* d_out, int out_size, void* d_ws, size_t ws_size,
                              hipStream_t stream) {
  const float* y0   = (const float*)d_in[0];  // [16,512]
  const float* bias = (const float*)d_in[1];  // [16,512,1]
  const float* adj  = (const float*)d_in[2];  // [16,512,512]
  const float* k0   = (const float*)d_in[3];  // [128,512,512]
  const float* k1   = (const float*)d_in[4];  // [128,512,128]
  const float* k2   = (const float*)d_in[5];  // [512,512,128]
  float* out = (float*)d_out;                 // [8,16,512] f32

  float* w      = (float*)d_ws;
  float* K0s    = w;               // 65536 floats
  float* K1s    = w + 65536;       // 16384
  float* M      = w + 81920;       // 65536
  float* s2T    = w + 147456;      // 2048  ([128][16] transposed)
  float* ybuf   = w + 149504;      // 16384 (2 x 8192, ping-pong)
  float* racc   = w + 165888;      // 8192
  float* aggp   = w + 174080;      // 16384 (2 halves x [16][512])
  float* rowinv = w + 190464;      // 262144 floats = 1 MB
  short* kq     = (short*)(w + 190464 + 262144);  // 33554432 shorts = 64 MB
  const bool useI16 =
      ws_size >= (size_t)(190464 + 262144) * 4 + (size_t)33554432 * 2;

  kPrep1<<<256, 256, 0, stream>>>(k0, K0s);
  kPrep2<<<64, 256, 0, stream>>>(k1, K1s);
  kPrep3<<<256, 256, 0, stream>>>(K0s, K1s, M);
  if (useI16) kConvRow<<<16384, 256, 0, stream>>>(k2, kq, rowinv);

  kA<<<64, 256, 0, stream>>>(y0, bias, M, aggp, ybuf, racc, s2T, out, 0, -1);

  for (int step = 0; step < 8; ++step) {
    for (int stage = 1; stage <= 4; ++stage) {
      if (useI16)
        kBi16<<<1024, 256, 0, stream>>>(kq, adj, s2T, rowinv, aggp);
      else
        kBf32<<<1024, 256, 0, stream>>>(k2, adj, s2T, aggp);
      kA<<<64, 256, 0, stream>>>(y0, bias, M, aggp, ybuf, racc, s2T, out, stage, step);
    }
  }
}